// Round 19
// baseline (452.193 us; speedup 1.0000x reference)
//
#include <hip/hip_runtime.h>
#include <stdint.h>

// Problem constants
#define Bb  8
#define Ss  4096
#define Dd  512
#define DIi 2048
#define Mm  (Bb*Ss)   // 32768 rows

typedef unsigned short u16;
typedef __bf16 bf16x8 __attribute__((ext_vector_type(8)));
typedef float  f32x4  __attribute__((ext_vector_type(4)));

__device__ __forceinline__ float bfu(unsigned int u) {
  return __uint_as_float((u & 0xffffu) << 16);
}
__device__ __forceinline__ u16 f2bu(float f) {
  unsigned int x = __float_as_uint(f);
  return (u16)((x + 0x7fffu + ((x >> 16) & 1u)) >> 16);  // RNE
}

// ================= fused prep: zero + conversions + 4 transposes =================
__device__ __forceinline__ void tr_tile(const float* __restrict__ W, u16* __restrict__ Wt,
                                        int K, int N, int local, int tid) {
  __shared__ float t[32][33];
  const int nx = N / 32;
  const int n0 = (local % nx) * 32, k0 = (local / nx) * 32;
  const int tx = tid & 31, ty = tid >> 5;   // 32 x 8
#pragma unroll
  for (int i = 0; i < 32; i += 8)
    t[ty + i][tx] = W[(long)(k0 + ty + i) * N + n0 + tx];
  __syncthreads();
#pragma unroll
  for (int i = 0; i < 32; i += 8)
    Wt[(long)(n0 + ty + i) * K + k0 + tx] = f2bu(t[tx][ty + i]);
}

__global__ __launch_bounds__(256) void prep(
    const float* __restrict__ x, u16* __restrict__ xb,
    const float* wv, const float* w1, const float* wo, const float* w2,
    const float* wq, const float* wk,
    u16* wvT, u16* w1T, u16* woT, u16* w2T, u16* wqb, u16* wkb,
    float* __restrict__ zptr) {
  const int bid = blockIdx.x, tid = threadIdx.x;
  if (bid < 320) {                       // zero 81920 floats (nksq,nqsq,kvp)
    zptr[bid * 256 + tid] = 0.f;
  } else if (bid < 2368) {               // conv x -> xb (grid-stride)
    long i = (long)(bid - 320) * 256 + tid;
    const long n4 = (long)Mm * Dd / 4;
    const long st = 2048L * 256;
    for (; i < n4; i += st) {
      float4 v = ((const float4*)x)[i];
      ushort4 o;
      o.x = f2bu(v.x); o.y = f2bu(v.y); o.z = f2bu(v.z); o.w = f2bu(v.w);
      ((ushort4*)xb)[i] = o;
    }
  } else if (bid < 3392)  tr_tile(wv, wvT, Dd, DIi, bid - 2368, tid);
  else if (bid < 4416)    tr_tile(w1, w1T, Dd, DIi, bid - 3392, tid);
  else if (bid < 5440)    tr_tile(wo, woT, DIi, Dd, bid - 4416, tid);
  else if (bid < 6464)    tr_tile(w2, w2T, DIi, Dd, bid - 5440, tid);
  else if (bid < 7488) {                 // conv wq -> wqb
    long i = (long)(bid - 6464) * 256 + tid;   // 262144 float4
    float4 v = ((const float4*)wq)[i];
    ushort4 o;
    o.x = f2bu(v.x); o.y = f2bu(v.y); o.z = f2bu(v.z); o.w = f2bu(v.w);
    ((ushort4*)wqb)[i] = o;
  } else {                               // conv wk -> wkb
    long i = (long)(bid - 7488) * 256 + tid;
    float4 v = ((const float4*)wk)[i];
    ushort4 o;
    o.x = f2bu(v.x); o.y = f2bu(v.y); o.z = f2bu(v.z); o.w = f2bu(v.w);
    ((ushort4*)wkb)[i] = o;
  }
}

// tr_x: xT[b][d][s] = x[b][s][d]; xrnT additionally scaled by rn[s]
__global__ void tr_x(const u16* __restrict__ xb, const float* __restrict__ nksq,
                     u16* __restrict__ xT, u16* __restrict__ xrnT) {
  __shared__ u16 t[32][33];
  __shared__ float rns[32];
  const int b = blockIdx.z;
  const int s0 = blockIdx.y * 32, d0 = blockIdx.x * 32;
  const int tx = threadIdx.x, ty = threadIdx.y;   // 32 x 8
  const size_t sbase = (size_t)b * Ss + s0;
#pragma unroll
  for (int i = 0; i < 32; i += 8)
    t[ty + i][tx] = xb[(sbase + ty + i) * Dd + d0 + tx];
  if (ty == 0) {
    const float nk = fmaxf(nksq[sbase + tx], 0.f);
    rns[tx] = 1.f / fmaxf(sqrtf(nk), 1e-12f);
  }
  __syncthreads();
  const size_t dbase = (size_t)b * Dd + d0;
#pragma unroll
  for (int i = 0; i < 32; i += 8) {
    const u16 v = t[tx][ty + i];
    const size_t idx = (dbase + ty + i) * Ss + s0 + tx;
    xT[idx] = v;
    xrnT[idx] = f2bu(bfu(v) * rns[tx]);
  }
}

#define GLL(src, dst) \
  __builtin_amdgcn_global_load_lds((const __attribute__((address_space(1))) unsigned int*)(src), \
                                   (__attribute__((address_space(3))) unsigned int*)(dst), 16, 0, 0)

// =================== 256^2-tile 8-wave pipelined GEMM (FFN only) ===================
// XCD-chunk remap: each XCD gets gridDim.y/8 contiguous row-panels (T1).
enum { G_FFN1 = 2, G_FFN2 = 3 };

template<int MODE>
__global__ __launch_bounds__(512, 2) void gemm8(
    const u16* __restrict__ A, const u16* __restrict__ Bt,
    int N, int K,
    u16* __restrict__ Ybf, float* __restrict__ Yf,
    const u16* __restrict__ resb, const float* __restrict__ bias)
{
  __shared__ u16 lds8[65536];   // 128 KB

  // bijective XCD-chunk remap (gridDim.y % 8 == 0 required; ours: 128)
  const int nxg = gridDim.x;
  const int s = blockIdx.y * nxg + blockIdx.x;
  const int xcd = s & 7, j = s >> 3;
  const int by = xcd * (gridDim.y >> 3) + j / nxg;
  const int bx = j % nxg;

  const int tid  = threadIdx.x;
  const int lane = tid & 63;
  const int wid  = tid >> 6;
  const int wr = wid >> 2, wc = wid & 3;
  const int l15 = lane & 15, lg = lane >> 4;

  const long bm0 = (long)by * 256;
  const long bn0 = (long)bx * 256;
  const int NT = K >> 6;

  const u16* pA = A + bm0 * K;
  const u16* pB = Bt + bn0 * K;

  const int rowT = ((tid >> 6) << 3) | (tid & 7);
  const int cc8  = ((tid >> 3) & 7) * 8;

#define STAGE(PTR, LD, H, TT, BUFU, REGU) do {                                  \
    const u16* s0_ = (PTR) + (size_t)((H) * 128 + rowT) * (LD)                  \
                     + (size_t)(TT) * 64 + cc8;                                 \
    u16* d_ = lds8 + (BUFU) + (REGU) + (H) * 8192 + wid * 512;                  \
    GLL(s0_, d_);                                                               \
    GLL(s0_ + (size_t)64 * (LD), d_ + 4096);                                    \
  } while (0)

  const int aoff = (wr * 16384 + (l15 >> 3) * 1024 + lg * 128 + (l15 & 7) * 16) >> 1;
  const int boff = (32768 + (wc >> 1) * 16384 + (wc & 1) * 8192 +
                    (l15 >> 3) * 1024 + lg * 128 + (l15 & 7) * 16) >> 1;
#define LDA(M_, KS_, BU_) (*(const bf16x8*)(lds8 + (BU_) + aoff + (M_) * 1024 + (KS_) * 256))
#define LDB(N_, KS_, BU_) (*(const bf16x8*)(lds8 + (BU_) + boff + (N_) * 1024 + (KS_) * 256))

  f32x4 acc[8][4] = {};

  STAGE(pA, K, 0, 0, 0, 0);
  STAGE(pA, K, 1, 0, 0, 0);
  STAGE(pB, K, 0, 0, 0, 16384);
  STAGE(pB, K, 1, 0, 0, 16384);
  STAGE(pA, K, 0, 1, 32768, 0);
  asm volatile("s_waitcnt vmcnt(2)" ::: "memory");
  __builtin_amdgcn_s_barrier();

  for (int t = 0; t < NT; ++t) {
    const int bufu = (t & 1) * 32768;
    const int nbuf = bufu ^ 32768;
    bf16x8 aF[4], bF[4];

#pragma unroll
    for (int n = 0; n < 4; ++n) bF[n] = LDB(n, 0, bufu);
#pragma unroll
    for (int m = 0; m < 4; ++m) aF[m] = LDA(m, 0, bufu);
    if (t + 1 < NT) STAGE(pA, K, 1, t + 1, nbuf, 0);
    __builtin_amdgcn_s_barrier();
    __builtin_amdgcn_s_setprio(1);
#pragma unroll
    for (int m = 0; m < 4; ++m)
#pragma unroll
      for (int n = 0; n < 4; ++n)
        acc[m][n] = __builtin_amdgcn_mfma_f32_16x16x32_bf16(aF[m], bF[n], acc[m][n], 0, 0, 0);
    __builtin_amdgcn_s_setprio(0);

#pragma unroll
    for (int m = 0; m < 4; ++m) aF[m] = LDA(4 + m, 0, bufu);
    if (t + 1 < NT) STAGE(pB, K, 0, t + 1, nbuf, 16384);
    __builtin_amdgcn_s_barrier();
    __builtin_amdgcn_s_setprio(1);
#pragma unroll
    for (int m = 0; m < 4; ++m)
#pragma unroll
      for (int n = 0; n < 4; ++n)
        acc[4 + m][n] = __builtin_amdgcn_mfma_f32_16x16x32_bf16(aF[m], bF[n], acc[4 + m][n], 0, 0, 0);
    __builtin_amdgcn_s_setprio(0);

#pragma unroll
    for (int n = 0; n < 4; ++n) bF[n] = LDB(n, 1, bufu);
#pragma unroll
    for (int m = 0; m < 4; ++m) aF[m] = LDA(m, 1, bufu);
    if (t + 1 < NT) STAGE(pB, K, 1, t + 1, nbuf, 16384);
    __builtin_amdgcn_s_barrier();
    __builtin_amdgcn_s_setprio(1);
#pragma unroll
    for (int m = 0; m < 4; ++m)
#pragma unroll
      for (int n = 0; n < 4; ++n)
        acc[m][n] = __builtin_amdgcn_mfma_f32_16x16x32_bf16(aF[m], bF[n], acc[m][n], 0, 0, 0);
    __builtin_amdgcn_s_setprio(0);

#pragma unroll
    for (int m = 0; m < 4; ++m) aF[m] = LDA(4 + m, 1, bufu);
    __builtin_amdgcn_s_barrier();
    __builtin_amdgcn_s_setprio(1);
#pragma unroll
    for (int m = 0; m < 4; ++m)
#pragma unroll
      for (int n = 0; n < 4; ++n)
        acc[4 + m][n] = __builtin_amdgcn_mfma_f32_16x16x32_bf16(aF[m], bF[n], acc[4 + m][n], 0, 0, 0);
    __builtin_amdgcn_s_setprio(0);

    if (t + 1 < NT) {
      __builtin_amdgcn_s_barrier();
      if (t + 2 < NT) {
        STAGE(pA, K, 0, t + 2, bufu, 0);
        asm volatile("s_waitcnt vmcnt(2)" ::: "memory");
      } else {
        asm volatile("s_waitcnt vmcnt(0)" ::: "memory");
      }
      __builtin_amdgcn_s_barrier();
    }
  }

#pragma unroll
  for (int m = 0; m < 8; ++m) {
    const long row0 = bm0 + wr * 128 + m * 16 + lg * 4;
#pragma unroll
    for (int n = 0; n < 4; ++n) {
      const long col = bn0 + wc * 64 + n * 16 + l15;
#pragma unroll
      for (int r = 0; r < 4; ++r) {
        const long idx = (row0 + r) * N + col;
        const float v = acc[m][n][r];
        if constexpr (MODE == G_FFN1) {
          float o = v + bias[col];
          o = o > 0.f ? o : 0.f;
          Ybf[idx] = f2bu(o);
        } else {  // G_FFN2
          Yf[idx] = v + bias[col] + bfu(resb[idx]);
        }
      }
    }
  }
#undef STAGE
#undef LDA
#undef LDB
}

// ====== mega64t: 64^2-tile z-sliced [512,2048]@[2048,512]^T -> transposed bf16 ======
// idx = z + zbase: 0: Gq = wqb@wqb^T -> Gt ; 1: Gk = wkb@wkb^T -> Gkt ;
// idx>=2: U_b = wqb @ (woT·kv_b)^T -> Ut[idx-2] — kv scale applied at frag-read
// time with the same f2bu rounding build_wob used (bit-identical Ut).
__global__ __launch_bounds__(256) void mega64t(
    const u16* __restrict__ wqb, const u16* __restrict__ wkb,
    const u16* __restrict__ woT, const float* __restrict__ kv,
    u16* __restrict__ Gt, u16* __restrict__ Gkt, u16* __restrict__ Ut, int zbase)
{
  __shared__ u16 As[2048];   // 4 KB (64 x 32)
  __shared__ u16 Bs[2048];   // 4 KB
  const int K = DIi;
  const int idx = blockIdx.z + zbase;
  const bool scaleB = (idx >= 2);
  const u16* A  = (idx == 1) ? wkb : wqb;
  const u16* Bt = (idx == 0) ? wqb : (idx == 1) ? wkb : woT;
  u16* Ct = (idx == 0) ? Gt : (idx == 1) ? Gkt
            : Ut + (size_t)(idx - 2) * Dd * Dd;
  const float* kvb = scaleB ? (kv + (size_t)(idx - 2) * DIi) : nullptr;

  const int tid = threadIdx.x, lane = tid & 63, w = tid >> 6;
  const int wr = w >> 1, wc = w & 1;           // 2x2 waves, 32x32 each
  const int l15 = lane & 15, lg = lane >> 4;
  const long bm0 = (long)blockIdx.y * 64;
  const long bn0 = (long)blockIdx.x * 64;

  const u16* aS0 = A  + (bm0 + (tid >> 2)) * K + (tid & 3) * 8;
  const u16* bS0 = Bt + (bn0 + (tid >> 2)) * K + (tid & 3) * 8;
  u16* aD0 = As + w * 512;   // wave-uniform base (HW adds lane*16B)
  u16* bD0 = Bs + w * 512;

  f32x4 acc[2][2] = {};

  for (int k0 = 0; k0 < K; k0 += 32) {
    GLL(aS0 + k0, aD0);
    GLL(bS0 + k0, bD0);
    __syncthreads();
    bf16x8 af[2], bfv[2];
#pragma unroll
    for (int m = 0; m < 2; ++m)
      af[m] = *(const bf16x8*)(As + (wr * 32 + m * 16 + l15) * 32 + lg * 8);
#pragma unroll
    for (int n = 0; n < 2; ++n)
      bfv[n] = *(const bf16x8*)(Bs + (wc * 32 + n * 16 + l15) * 32 + lg * 8);
    if (scaleB) {
      const float* kp = kvb + k0 + lg * 8;
      float kvv[8];
#pragma unroll
      for (int j = 0; j < 8; ++j) kvv[j] = kp[j];
#pragma unroll
      for (int n = 0; n < 2; ++n) {
        u16* bp = (u16*)&bfv[n];
#pragma unroll
        for (int j = 0; j < 8; ++j) bp[j] = f2bu(bfu(bp[j]) * kvv[j]);
      }
    }
#pragma unroll
    for (int m = 0; m < 2; ++m)
#pragma unroll
      for (int n = 0; n < 2; ++n)
        acc[m][n] = __builtin_amdgcn_mfma_f32_16x16x32_bf16(af[m], bfv[n], acc[m][n], 0, 0, 0);
    __syncthreads();
  }

  // transposed store: Ct[col][row0..3] (rows consecutive -> ushort4)
#pragma unroll
  for (int m = 0; m < 2; ++m) {
    const int row0 = (int)bm0 + wr * 32 + m * 16 + lg * 4;
#pragma unroll
    for (int n = 0; n < 2; ++n) {
      const int col = (int)bn0 + wc * 32 + n * 16 + l15;
      ushort4 o;
      o.x = f2bu(acc[m][n][0]); o.y = f2bu(acc[m][n][1]);
      o.z = f2bu(acc[m][n][2]); o.w = f2bu(acc[m][n][3]);
      *(ushort4*)(Ct + (size_t)col * Dd + row0) = o;
    }
  }
}

// ====== megacb: C_b = xrnT_b @ xT_b^T, 64x64 tiles, grid (8,8,Bb)=512 blocks ======
// per-z XCD remap: by=xcd, bx=j -> each XCD owns one A row-panel + all 8 col-blocks.
__global__ __launch_bounds__(256) void megacb(
    const u16* __restrict__ xrnT, const u16* __restrict__ xT,
    u16* __restrict__ Cb)
{
  __shared__ u16 As[2048];   // 4 KB (64 x 32)
  __shared__ u16 Bs[2048];   // 4 KB
  const int K = Ss;
  const int z = blockIdx.z;
  const u16* A  = xrnT + (size_t)z * Dd * Ss;
  const u16* Bt = xT   + (size_t)z * Dd * Ss;
  u16* C = Cb + (size_t)z * Dd * Dd;

  // per-z-slice remap (64 blocks, offset z*64 ≡ 0 mod 8)
  const int s = blockIdx.y * 8 + blockIdx.x;
  const int byR = s & 7;          // xcd
  const int bxR = s >> 3;         // 0..7

  const int tid = threadIdx.x, lane = tid & 63, w = tid >> 6;
  const int wr = w >> 1, wc = w & 1;           // 2x2 waves, 32x32 each
  const int l15 = lane & 15, lg = lane >> 4;
  const long bm0 = (long)byR * 64;
  const long bn0 = (long)bxR * 64;

  const u16* aS0 = A  + (bm0 + (tid >> 2)) * K + (tid & 3) * 8;
  const u16* bS0 = Bt + (bn0 + (tid >> 2)) * K + (tid & 3) * 8;
  u16* aD0 = As + w * 512;
  u16* bD0 = Bs + w * 512;

  f32x4 acc[2][2] = {};

  for (int k0 = 0; k0 < K; k0 += 32) {
    GLL(aS0 + k0, aD0);
    GLL(bS0 + k0, bD0);
    __syncthreads();
    bf16x8 af[2], bfv[2];
#pragma unroll
    for (int m = 0; m < 2; ++m)
      af[m] = *(const bf16x8*)(As + (wr * 32 + m * 16 + l15) * 32 + lg * 8);
#pragma unroll
    for (int n = 0; n < 2; ++n)
      bfv[n] = *(const bf16x8*)(Bs + (wc * 32 + n * 16 + l15) * 32 + lg * 8);
#pragma unroll
    for (int m = 0; m < 2; ++m)
#pragma unroll
      for (int n = 0; n < 2; ++n)
        acc[m][n] = __builtin_amdgcn_mfma_f32_16x16x32_bf16(af[m], bfv[n], acc[m][n], 0, 0, 0);
    __syncthreads();
  }

#pragma unroll
  for (int m = 0; m < 2; ++m) {
    const long row0 = bm0 + wr * 32 + m * 16 + lg * 4;
#pragma unroll
    for (int n = 0; n < 2; ++n) {
      const long col = bn0 + wc * 32 + n * 16 + l15;
#pragma unroll
      for (int r = 0; r < 4; ++r)
        C[(row0 + r) * Dd + col] = f2bu(acc[m][n][r]);
    }
  }
}

// ====== megatb: acc = C_b @ wv tile; FUSED colsum epilogue:
//        kv[b,e] += sum over block's 128 d-rows of wkb[d,e] * acc  (no T_b) ======
__global__ __launch_bounds__(256) void megatb(
    const u16* __restrict__ Cb, const u16* __restrict__ wvT,
    const u16* __restrict__ wkb, float* __restrict__ kv)
{
  __shared__ u16 As[4096];
  __shared__ u16 Bs[4096];
  const int K = Dd;
  const int z = blockIdx.z;
  const u16* A = Cb + (size_t)z * Dd * Dd;

  const int tid = threadIdx.x, lane = tid & 63, w = tid >> 6;
  const int wr = w >> 1, wc = w & 1;
  const int l15 = lane & 15, lg = lane >> 4;
  const long bm0 = (long)blockIdx.y * 128;   // d rows
  const long bn0 = (long)blockIdx.x * 128;   // e cols

  const int c0 = tid, c1 = tid + 256;
  const u16* aS0 = A   + (bm0 + (c0 >> 2)) * K + (c0 & 3) * 8;
  const u16* aS1 = A   + (bm0 + (c1 >> 2)) * K + (c1 & 3) * 8;
  const u16* bS0 = wvT + (bn0 + (c0 >> 2)) * K + (c0 & 3) * 8;
  const u16* bS1 = wvT + (bn0 + (c1 >> 2)) * K + (c1 & 3) * 8;
  u16* aD0 = As + w * 512;
  u16* aD1 = As + 2048 + w * 512;
  u16* bD0 = Bs + w * 512;
  u16* bD1 = Bs + 2048 + w * 512;

  f32x4 acc[4][4] = {};

  for (int k0 = 0; k0 < K; k0 += 32) {
    GLL(aS0 + k0, aD0);
    GLL(aS1 + k0, aD1);
    GLL(bS0 + k0, bD0);
    GLL(bS1 + k0, bD1);
    __syncthreads();
    bf16x8 af[4], bfv[4];
#pragma unroll
    for (int m = 0; m < 4; ++m)
      af[m] = *(const bf16x8*)(As + (wr * 64 + m * 16 + l15) * 32 + lg * 8);
#pragma unroll
    for (int n = 0; n < 4; ++n)
      bfv[n] = *(const bf16x8*)(Bs + (wc * 64 + n * 16 + l15) * 32 + lg * 8);
#pragma unroll
    for (int m = 0; m < 4; ++m)
#pragma unroll
      for (int n = 0; n < 4; ++n)
        acc[m][n] = __builtin_amdgcn_mfma_f32_16x16x32_bf16(af[m], bfv[n], acc[m][n], 0, 0, 0);
    __syncthreads();
  }

  // fused colsum: cs[n] = sum over this thread's 16 d-rows of wkb[d,e]*T[d,e]
  float cs[4] = {0.f, 0.f, 0.f, 0.f};
#pragma unroll
  for (int m = 0; m < 4; ++m) {
    const long drow0 = bm0 + wr * 64 + m * 16 + lg * 4;
#pragma unroll
    for (int n = 0; n < 4; ++n) {
      const long col = bn0 + wc * 64 + n * 16 + l15;
#pragma unroll
      for (int r = 0; r < 4; ++r)
        cs[n] += bfu(wkb[(drow0 + r) * DIi + col]) * acc[m][n][r];
    }
  }
#pragma unroll
  for (int n = 0; n < 4; ++n) {          // reduce over lg (64 rows per wave)
    cs[n] += __shfl_xor(cs[n], 16, 64);
    cs[n] += __shfl_xor(cs[n], 32, 64);
  }
  if (lane < 16) {
#pragma unroll
    for (int n = 0; n < 4; ++n) {
      const long col = bn0 + wc * 64 + n * 16 + l15;
      atomicAdd(&kv[(size_t)z * DIi + col], cs[n]);
    }
  }
}

// ====== mega_nx: M x 512 GEMM (K=512) with x-restage epilogue ======
// MODE 0 (dual Gram): rows [0,Mm): nqsq via Gt; rows [Mm,2Mm): nksq via Gkt
// MODE 1 (AWO): acc = x@U_b tile; attnb = bf16(acc*rsqrt(nqsq) + x)
// XCD-chunk remap (T1): all 4 col-blocks of a row-panel on one XCD.
template<int MODE>
__global__ __launch_bounds__(256) void mega_nx(
    const u16* __restrict__ xb, const u16* __restrict__ Gt, const u16* __restrict__ Gkt,
    const u16* __restrict__ Ut,
    float* __restrict__ nqsq, float* __restrict__ nksq, u16* __restrict__ attnb)
{
  __shared__ u16 As[4096];    // 8 KB
  __shared__ u16 Bs[4096];    // 8 KB
  __shared__ u16 xs[16384];   // 32 KB x-tile restage
  const int K = Dd, N = Dd;

  // bijective XCD-chunk remap (gridDim.y: 512 or 256, both % 8 == 0; nx=4)
  const int nxg = gridDim.x;
  const int sId = blockIdx.y * nxg + blockIdx.x;
  const int xcd = sId & 7, jId = sId >> 3;
  const int byR = xcd * (gridDim.y >> 3) + jId / nxg;
  const int bxR = jId % nxg;

  const int tid = threadIdx.x, lane = tid & 63, w = tid >> 6;
  const int wr = w >> 1, wc = w & 1;
  const int l15 = lane & 15, lg = lane >> 4;
  const bool isK = (MODE == 0) && (byR >= Mm / 128);
  const long bm0 = (long)(isK ? byR - Mm / 128 : byR) * 128;
  const long bn0 = (long)bxR * 128;
  const int bq = (int)(bm0 >> 12);
  const u16* Bt = (MODE == 0) ? (isK ? Gkt : Gt) : Ut + (size_t)bq * Dd * Dd;
  float* nsq = (MODE == 0) ? (isK ? nksq : nqsq) : nqsq;

  const int c0 = tid, c1 = tid + 256;
  const u16* aS0 = xb + (bm0 + (c0 >> 2)) * K + (c0 & 3) * 8;
  const u16* aS1 = xb + (bm0 + (c1 >> 2)) * K + (c1 & 3) * 8;
  const u16* bS0 = Bt + (bn0 + (c0 >> 2)) * K + (c0 & 3) * 8;
  const u16* bS1 = Bt + (bn0 + (c1 >> 2)) * K + (c1 & 3) * 8;
  u16* aD0 = As + w * 512;
  u16* aD1 = As + 2048 + w * 512;
  u16* bD0 = Bs + w * 512;
  u16* bD1 = Bs + 2048 + w * 512;

  f32x4 acc[4][4] = {};

  for (int k0 = 0; k0 < K; k0 += 32) {
    GLL(aS0 + k0, aD0);
    GLL(aS1 + k0, aD1);
    GLL(bS0 + k0, bD0);
    GLL(bS1 + k0, bD1);
    __syncthreads();
    bf16x8 af[4], bfv[4];
#pragma unroll
    for (int m = 0; m < 4; ++m)
      af[m] = *(const bf16x8*)(As + (wr * 64 + m * 16 + l15) * 32 + lg * 8);
#pragma unroll
    for (int n = 0; n < 4; ++n)
      bfv[n] = *(const bf16x8*)(Bs + (wc * 64 + n * 16 + l15) * 32 + lg * 8);
#pragma unroll
    for (int m = 0; m < 4; ++m)
#pragma unroll
      for (int n = 0; n < 4; ++n)
        acc[m][n] = __builtin_amdgcn_mfma_f32_16x16x32_bf16(af[m], bfv[n], acc[m][n], 0, 0, 0);
    __syncthreads();
  }

  // restage block's x tile [128 rows x 128 cols] with slot-XOR swizzle
#pragma unroll
  for (int i = 0; i < 8; ++i) {
    const int c = i * 256 + tid;
    const int rowL = c >> 4;
    const int srcslot = (c & 15) ^ (rowL & 15);
    const u16* src = xb + (size_t)(bm0 + rowL) * Dd + bn0 + srcslot * 8;
    GLL(src, xs + i * 2048 + w * 512);
  }
  asm volatile("s_waitcnt vmcnt(0)" ::: "memory");
  __builtin_amdgcn_s_barrier();

#define XV(RL, CL) bfu(xs[(RL) * 128 + ((((CL) >> 3) ^ ((RL) & 15)) << 3) + ((CL) & 7)])

  if constexpr (MODE == 0) {
    float sk[16];
#pragma unroll
    for (int i = 0; i < 16; ++i) sk[i] = 0.f;
#pragma unroll
    for (int m = 0; m < 4; ++m) {
#pragma unroll
      for (int n = 0; n < 4; ++n) {
        const int colL = wc * 64 + n * 16 + l15;
#pragma unroll
        for (int r = 0; r < 4; ++r) {
          const int rowL = wr * 64 + m * 16 + lg * 4 + r;
          sk[m * 4 + r] += acc[m][n][r] * XV(rowL, colL);
        }
      }
    }
#pragma unroll
    for (int i = 0; i < 16; ++i) {
#pragma unroll
      for (int off = 1; off < 16; off <<= 1)
        sk[i] += __shfl_xor(sk[i], off, 64);
    }
    if (l15 == 0) {
#pragma unroll
      for (int m = 0; m < 4; ++m)
#pragma unroll
        for (int r = 0; r < 4; ++r)
          atomicAdd(&nsq[bm0 + wr * 64 + m * 16 + lg * 4 + r], sk[m * 4 + r]);
    }
  } else {
#pragma unroll
    for (int m = 0; m < 4; ++m) {
      const long row0 = bm0 + wr * 64 + m * 16 + lg * 4;
      float rq[4];
#pragma unroll
      for (int r = 0; r < 4; ++r)
        rq[r] = 1.f / fmaxf(sqrtf(fmaxf(nqsq[row0 + r], 0.f)), 1e-12f);
#pragma unroll
      for (int n = 0; n < 4; ++n) {
        const int colL = wc * 64 + n * 16 + l15;
#pragma unroll
        for (int r = 0; r < 4; ++r) {
          const int rowL = wr * 64 + m * 16 + lg * 4 + r;
          attnb[(row0 + r) * N + bn0 + colL] = f2bu(acc[m][n][r] * rq[r] + XV(rowL, colL));
        }
      }
    }
  }
#undef XV
}

extern "C" void kernel_launch(void* const* d_in, const int* in_sizes, int n_in,
                              void* d_out, int out_size, void* d_ws, size_t ws_size,
                              hipStream_t stream) {
  const float* x  = (const float*)d_in[0];
  const float* wq = (const float*)d_in[1];
  const float* wk = (const float*)d_in[2];
  const float* wv = (const float*)d_in[3];
  const float* wo = (const float*)d_in[4];
  const float* w1 = (const float*)d_in[5];
  const float* b1 = (const float*)d_in[6];
  const float* w2 = (const float*)d_in[7];
  const float* b2 = (const float*)d_in[8];
  float* out = (float*)d_out;

  // workspace carve-up: ~219.5 MB total (ws_size evidence: 236 MB OK, 324 MB faults)
  char* p = (char*)d_ws;
  auto take = [&](size_t bytes) {
    char* r = p; p += (bytes + 255) & ~(size_t)255; return r;
  };
  u16*   xb    = (u16*)take((size_t)Mm * Dd * 2);        // 33.5 MB
  u16*   wvT   = (u16*)take((size_t)DIi * Dd * 2);
  u16*   w1T   = (u16*)take((size_t)DIi * Dd * 2);
  u16*   woT   = (u16*)take((size_t)Dd * DIi * 2);
  u16*   w2T   = (u16*)take((size_t)Dd * DIi * 2);
  u16*   wqb   = (u16*)take((size_t)Dd * DIi * 2);
  u16*   wkb   = (u16*)take((size_t)Dd * DIi * 2);
  u16*   Gt    = (u16*)take((size_t)Dd * Dd * 2);
  u16*   Gkt   = (u16*)take((size_t)Dd * Dd * 2);
  u16*   Ut    = (u16*)take((size_t)Bb * Dd * Dd * 2);   // 4.2 MB
  u16*   buf1  = (u16*)take((size_t)Mm * DIi * 2);       // 134 MB: pre-FFN scratch, then h
  u16*   attnb = (u16*)take((size_t)Mm * Dd * 2);        // 33.5 MB
  float* nksq  = (float*)take((size_t)Mm * 4);           // contiguous: nksq,nqsq,kvp
  float* nqsq  = (float*)take((size_t)Mm * 4);
  float* kvp   = (float*)take((size_t)Bb * DIi * 4);
  // sub-carve inside buf1 — all lifetimes end before FFN1 writes h into buf1
  u16* xT   = buf1;                                          // 33.5 MB
  u16* xrnT = buf1 + (size_t)Mm * Dd;                        // 33.5 MB
  u16* Cb   = buf1 + 2 * (size_t)Mm * Dd;                    // 4.2 MB (ends 71.2 MB)
  (void)in_sizes; (void)n_in; (void)out_size; (void)ws_size;

  // prep: zero(nksq,nqsq,kvp) + conv x + tr wv/w1/wo/w2 + conv wq/wk
  prep<<<8512, 256, 0, stream>>>(x, xb, wv, w1, wo, w2, wq, wk,
                                 wvT, w1T, woT, w2T, wqb, wkb, nksq);

  // Gq = wqb@wqb^T ; Gk = wkb@wkb^T  (64^2 tiles, 128 blocks)
  mega64t<<<dim3(8, 8, 2), 256, 0, stream>>>(
      wqb, wkb, woT, kvp, Gt, Gkt, Ut, 0);

  // nqsq & nksq in one dispatch: rowdot(x@G, x)
  mega_nx<0><<<dim3(4, 2 * Mm / 128), 256, 0, stream>>>(
      xb, Gt, Gkt, nullptr, nqsq, nksq, nullptr);

  // xT / xrnT (rn = rsqrt(nksq) folded)
  tr_x<<<dim3(Dd / 32, Ss / 32, Bb), dim3(32, 8), 0, stream>>>(xb, nksq, xT, xrnT);

  // C_b = xrnT_b @ xT_b^T   [512x512 per batch], 64^2 tiles, 512 blocks
  megacb<<<dim3(8, 8, Bb), 256, 0, stream>>>(xrnT, xT, Cb);

  // kv[b,e] += colsum( wkb ⊙ (C_b @ wv) )  — fused, no T_b materialization
  megatb<<<dim3(16, 4, Bb), 256, 0, stream>>>(Cb, wvT, wkb, kvp);

  // U_b = wqb @ (woT·kv_b)^T -> Ut  (64^2 tiles, 512 blocks; kv folded in-frag)
  mega64t<<<dim3(8, 8, 8), 256, 0, stream>>>(
      wqb, wkb, woT, kvp, Gt, Gkt, Ut, 2);

  // attn = (x@U_b)*rsqrt(nqsq) + x -> attnb
  mega_nx<1><<<dim3(4, Mm / 128), 256, 0, stream>>>(
      xb, nullptr, nullptr, Ut, nqsq, nullptr, attnb);

  // h = relu(attn @ w1 + b1) -> buf1 (overwrites dead xT/xrnT/Cb)
  gemm8<G_FFN1><<<dim3(DIi / 256, Mm / 256), 512, 0, stream>>>(
      attnb, w1T, DIi, Dd, buf1, nullptr, nullptr, b1);

  // out = h @ w2 + b2 + attn
  gemm8<G_FFN2><<<dim3(Dd / 256, Mm / 256), 512, 0, stream>>>(
      buf1, w2T, Dd, DIi, nullptr, out, attnb, b2);
}

// Round 20
// 444.705 us; speedup vs baseline: 1.0168x; 1.0168x over previous
//
#include <hip/hip_runtime.h>
#include <stdint.h>

// Problem constants
#define Bb  8
#define Ss  4096
#define Dd  512
#define DIi 2048
#define Mm  (Bb*Ss)   // 32768 rows

typedef unsigned short u16;
typedef __bf16 bf16x8 __attribute__((ext_vector_type(8)));
typedef float  f32x4  __attribute__((ext_vector_type(4)));

__device__ __forceinline__ float bfu(unsigned int u) {
  return __uint_as_float((u & 0xffffu) << 16);
}
__device__ __forceinline__ u16 f2bu(float f) {
  unsigned int x = __float_as_uint(f);
  return (u16)((x + 0x7fffu + ((x >> 16) & 1u)) >> 16);  // RNE
}

// ================= fused prep: zero + conversions + 4 transposes =================
__device__ __forceinline__ void tr_tile(const float* __restrict__ W, u16* __restrict__ Wt,
                                        int K, int N, int local, int tid) {
  __shared__ float t[32][33];
  const int nx = N / 32;
  const int n0 = (local % nx) * 32, k0 = (local / nx) * 32;
  const int tx = tid & 31, ty = tid >> 5;   // 32 x 8
#pragma unroll
  for (int i = 0; i < 32; i += 8)
    t[ty + i][tx] = W[(long)(k0 + ty + i) * N + n0 + tx];
  __syncthreads();
#pragma unroll
  for (int i = 0; i < 32; i += 8)
    Wt[(long)(n0 + ty + i) * K + k0 + tx] = f2bu(t[tx][ty + i]);
}

__global__ __launch_bounds__(256) void prep(
    const float* __restrict__ x, u16* __restrict__ xb,
    const float* wv, const float* w1, const float* wo, const float* w2,
    const float* wq, const float* wk,
    u16* wvT, u16* w1T, u16* woT, u16* w2T, u16* wqb, u16* wkb,
    float* __restrict__ zptr) {
  const int bid = blockIdx.x, tid = threadIdx.x;
  if (bid < 320) {                       // zero 81920 floats (nksq,nqsq,kvp)
    zptr[bid * 256 + tid] = 0.f;
  } else if (bid < 2368) {               // conv x -> xb (grid-stride)
    long i = (long)(bid - 320) * 256 + tid;
    const long n4 = (long)Mm * Dd / 4;
    const long st = 2048L * 256;
    for (; i < n4; i += st) {
      float4 v = ((const float4*)x)[i];
      ushort4 o;
      o.x = f2bu(v.x); o.y = f2bu(v.y); o.z = f2bu(v.z); o.w = f2bu(v.w);
      ((ushort4*)xb)[i] = o;
    }
  } else if (bid < 3392)  tr_tile(wv, wvT, Dd, DIi, bid - 2368, tid);
  else if (bid < 4416)    tr_tile(w1, w1T, Dd, DIi, bid - 3392, tid);
  else if (bid < 5440)    tr_tile(wo, woT, DIi, Dd, bid - 4416, tid);
  else if (bid < 6464)    tr_tile(w2, w2T, DIi, Dd, bid - 5440, tid);
  else if (bid < 7488) {                 // conv wq -> wqb
    long i = (long)(bid - 6464) * 256 + tid;   // 262144 float4
    float4 v = ((const float4*)wq)[i];
    ushort4 o;
    o.x = f2bu(v.x); o.y = f2bu(v.y); o.z = f2bu(v.z); o.w = f2bu(v.w);
    ((ushort4*)wqb)[i] = o;
  } else {                               // conv wk -> wkb
    long i = (long)(bid - 7488) * 256 + tid;
    float4 v = ((const float4*)wk)[i];
    ushort4 o;
    o.x = f2bu(v.x); o.y = f2bu(v.y); o.z = f2bu(v.z); o.w = f2bu(v.w);
    ((ushort4*)wkb)[i] = o;
  }
}

// wob[b][n][k] = woT[n][k] * kv[b][k]
__global__ __launch_bounds__(256) void build_wob(const u16* __restrict__ woT,
                                                 const float* __restrict__ kv,
                                                 u16* __restrict__ wob) {
  const int b = blockIdx.y;
  long i = (long)blockIdx.x * 256 + threadIdx.x;
  const long tot = (long)Dd * DIi / 8;
  if (i >= tot) return;
  const long e = i * 8;
  const int k = (int)(e & (DIi - 1));
  ushort4 w0 = *(const ushort4*)(woT + e);
  ushort4 w1 = *(const ushort4*)(woT + e + 4);
  const float* kvp = kv + (long)b * DIi + k;
  ushort4 o0, o1;
  o0.x = f2bu(bfu(w0.x) * kvp[0]); o0.y = f2bu(bfu(w0.y) * kvp[1]);
  o0.z = f2bu(bfu(w0.z) * kvp[2]); o0.w = f2bu(bfu(w0.w) * kvp[3]);
  o1.x = f2bu(bfu(w1.x) * kvp[4]); o1.y = f2bu(bfu(w1.y) * kvp[5]);
  o1.z = f2bu(bfu(w1.z) * kvp[6]); o1.w = f2bu(bfu(w1.w) * kvp[7]);
  u16* dst = wob + (long)b * Dd * DIi + e;
  *(ushort4*)dst = o0;
  *(ushort4*)(dst + 4) = o1;
}

// tr_x: xT[b][d][s] = x[b][s][d]; xrnT additionally scaled by rn[s]
__global__ void tr_x(const u16* __restrict__ xb, const float* __restrict__ nksq,
                     u16* __restrict__ xT, u16* __restrict__ xrnT) {
  __shared__ u16 t[32][33];
  __shared__ float rns[32];
  const int b = blockIdx.z;
  const int s0 = blockIdx.y * 32, d0 = blockIdx.x * 32;
  const int tx = threadIdx.x, ty = threadIdx.y;   // 32 x 8
  const size_t sbase = (size_t)b * Ss + s0;
#pragma unroll
  for (int i = 0; i < 32; i += 8)
    t[ty + i][tx] = xb[(sbase + ty + i) * Dd + d0 + tx];
  if (ty == 0) {
    const float nk = fmaxf(nksq[sbase + tx], 0.f);
    rns[tx] = 1.f / fmaxf(sqrtf(nk), 1e-12f);
  }
  __syncthreads();
  const size_t dbase = (size_t)b * Dd + d0;
#pragma unroll
  for (int i = 0; i < 32; i += 8) {
    const u16 v = t[tx][ty + i];
    const size_t idx = (dbase + ty + i) * Ss + s0 + tx;
    xT[idx] = v;
    xrnT[idx] = f2bu(bfu(v) * rns[tx]);
  }
}

// colsum_kv v2: kv[b,e] += sum_{d in chunk} wkb[d,e]*Tb[b,d,e]  (512 blocks)
__global__ __launch_bounds__(256) void colsum_kv(const u16* __restrict__ wkb,
                                                 const u16* __restrict__ Tb,
                                                 float* __restrict__ kv) {
  const int b = blockIdx.y;
  const int e = blockIdx.x * 256 + threadIdx.x;
  const int d0 = blockIdx.z * 64;
  const u16* wp = wkb + (size_t)d0 * DIi + e;
  const u16* tp = Tb + (size_t)b * Dd * DIi + (size_t)d0 * DIi + e;
  float a = 0.f;
#pragma unroll 4
  for (int d = 0; d < 64; ++d) {
    a += bfu(wp[0]) * bfu(tp[0]);
    wp += DIi; tp += DIi;
  }
  atomicAdd(&kv[(size_t)b * DIi + e], a);
}

#define GLL(src, dst) \
  __builtin_amdgcn_global_load_lds((const __attribute__((address_space(1))) unsigned int*)(src), \
                                   (__attribute__((address_space(3))) unsigned int*)(dst), 16, 0, 0)

// =================== 256^2-tile 8-wave pipelined GEMM (FFN only) ===================
// XCD-chunk remap: each XCD gets gridDim.y/8 contiguous row-panels (T1).
enum { G_FFN1 = 2, G_FFN2 = 3 };

template<int MODE>
__global__ __launch_bounds__(512, 2) void gemm8(
    const u16* __restrict__ A, const u16* __restrict__ Bt,
    int N, int K,
    u16* __restrict__ Ybf, float* __restrict__ Yf,
    const u16* __restrict__ resb, const float* __restrict__ bias)
{
  __shared__ u16 lds8[65536];   // 128 KB

  // bijective XCD-chunk remap (gridDim.y % 8 == 0 required; ours: 128)
  const int nxg = gridDim.x;
  const int s = blockIdx.y * nxg + blockIdx.x;
  const int xcd = s & 7, j = s >> 3;
  const int by = xcd * (gridDim.y >> 3) + j / nxg;
  const int bx = j % nxg;

  const int tid  = threadIdx.x;
  const int lane = tid & 63;
  const int wid  = tid >> 6;
  const int wr = wid >> 2, wc = wid & 3;
  const int l15 = lane & 15, lg = lane >> 4;

  const long bm0 = (long)by * 256;
  const long bn0 = (long)bx * 256;
  const int NT = K >> 6;

  const u16* pA = A + bm0 * K;
  const u16* pB = Bt + bn0 * K;

  const int rowT = ((tid >> 6) << 3) | (tid & 7);
  const int cc8  = ((tid >> 3) & 7) * 8;

#define STAGE(PTR, LD, H, TT, BUFU, REGU) do {                                  \
    const u16* s0_ = (PTR) + (size_t)((H) * 128 + rowT) * (LD)                  \
                     + (size_t)(TT) * 64 + cc8;                                 \
    u16* d_ = lds8 + (BUFU) + (REGU) + (H) * 8192 + wid * 512;                  \
    GLL(s0_, d_);                                                               \
    GLL(s0_ + (size_t)64 * (LD), d_ + 4096);                                    \
  } while (0)

  const int aoff = (wr * 16384 + (l15 >> 3) * 1024 + lg * 128 + (l15 & 7) * 16) >> 1;
  const int boff = (32768 + (wc >> 1) * 16384 + (wc & 1) * 8192 +
                    (l15 >> 3) * 1024 + lg * 128 + (l15 & 7) * 16) >> 1;
#define LDA(M_, KS_, BU_) (*(const bf16x8*)(lds8 + (BU_) + aoff + (M_) * 1024 + (KS_) * 256))
#define LDB(N_, KS_, BU_) (*(const bf16x8*)(lds8 + (BU_) + boff + (N_) * 1024 + (KS_) * 256))

  f32x4 acc[8][4] = {};

  STAGE(pA, K, 0, 0, 0, 0);
  STAGE(pA, K, 1, 0, 0, 0);
  STAGE(pB, K, 0, 0, 0, 16384);
  STAGE(pB, K, 1, 0, 0, 16384);
  STAGE(pA, K, 0, 1, 32768, 0);
  asm volatile("s_waitcnt vmcnt(2)" ::: "memory");
  __builtin_amdgcn_s_barrier();

  for (int t = 0; t < NT; ++t) {
    const int bufu = (t & 1) * 32768;
    const int nbuf = bufu ^ 32768;
    bf16x8 aF[4], bF[4];

#pragma unroll
    for (int n = 0; n < 4; ++n) bF[n] = LDB(n, 0, bufu);
#pragma unroll
    for (int m = 0; m < 4; ++m) aF[m] = LDA(m, 0, bufu);
    if (t + 1 < NT) STAGE(pA, K, 1, t + 1, nbuf, 0);
    __builtin_amdgcn_s_barrier();
    __builtin_amdgcn_s_setprio(1);
#pragma unroll
    for (int m = 0; m < 4; ++m)
#pragma unroll
      for (int n = 0; n < 4; ++n)
        acc[m][n] = __builtin_amdgcn_mfma_f32_16x16x32_bf16(aF[m], bF[n], acc[m][n], 0, 0, 0);
    __builtin_amdgcn_s_setprio(0);

#pragma unroll
    for (int m = 0; m < 4; ++m) aF[m] = LDA(4 + m, 0, bufu);
    if (t + 1 < NT) STAGE(pB, K, 0, t + 1, nbuf, 16384);
    __builtin_amdgcn_s_barrier();
    __builtin_amdgcn_s_setprio(1);
#pragma unroll
    for (int m = 0; m < 4; ++m)
#pragma unroll
      for (int n = 0; n < 4; ++n)
        acc[4 + m][n] = __builtin_amdgcn_mfma_f32_16x16x32_bf16(aF[m], bF[n], acc[4 + m][n], 0, 0, 0);
    __builtin_amdgcn_s_setprio(0);

#pragma unroll
    for (int n = 0; n < 4; ++n) bF[n] = LDB(n, 1, bufu);
#pragma unroll
    for (int m = 0; m < 4; ++m) aF[m] = LDA(m, 1, bufu);
    if (t + 1 < NT) STAGE(pB, K, 1, t + 1, nbuf, 16384);
    __builtin_amdgcn_s_barrier();
    __builtin_amdgcn_s_setprio(1);
#pragma unroll
    for (int m = 0; m < 4; ++m)
#pragma unroll
      for (int n = 0; n < 4; ++n)
        acc[m][n] = __builtin_amdgcn_mfma_f32_16x16x32_bf16(aF[m], bF[n], acc[m][n], 0, 0, 0);
    __builtin_amdgcn_s_setprio(0);

#pragma unroll
    for (int m = 0; m < 4; ++m) aF[m] = LDA(4 + m, 1, bufu);
    __builtin_amdgcn_s_barrier();
    __builtin_amdgcn_s_setprio(1);
#pragma unroll
    for (int m = 0; m < 4; ++m)
#pragma unroll
      for (int n = 0; n < 4; ++n)
        acc[4 + m][n] = __builtin_amdgcn_mfma_f32_16x16x32_bf16(aF[m], bF[n], acc[4 + m][n], 0, 0, 0);
    __builtin_amdgcn_s_setprio(0);

    if (t + 1 < NT) {
      __builtin_amdgcn_s_barrier();
      if (t + 2 < NT) {
        STAGE(pA, K, 0, t + 2, bufu, 0);
        asm volatile("s_waitcnt vmcnt(2)" ::: "memory");
      } else {
        asm volatile("s_waitcnt vmcnt(0)" ::: "memory");
      }
      __builtin_amdgcn_s_barrier();
    }
  }

#pragma unroll
  for (int m = 0; m < 8; ++m) {
    const long row0 = bm0 + wr * 128 + m * 16 + lg * 4;
#pragma unroll
    for (int n = 0; n < 4; ++n) {
      const long col = bn0 + wc * 64 + n * 16 + l15;
#pragma unroll
      for (int r = 0; r < 4; ++r) {
        const long idx = (row0 + r) * N + col;
        const float v = acc[m][n][r];
        if constexpr (MODE == G_FFN1) {
          float o = v + bias[col];
          o = o > 0.f ? o : 0.f;
          Ybf[idx] = f2bu(o);
        } else {  // G_FFN2
          Yf[idx] = v + bias[col] + bfu(resb[idx]);
        }
      }
    }
  }
#undef STAGE
#undef LDA
#undef LDB
}

// ====== mega64t: 64^2-tile z-sliced [512,2048]@[2048,512]^T -> transposed bf16 ======
__global__ __launch_bounds__(256) void mega64t(
    const u16* __restrict__ wqb, const u16* __restrict__ wkb,
    const u16* __restrict__ wob,
    u16* __restrict__ Gt, u16* __restrict__ Gkt, u16* __restrict__ Ut, int zbase)
{
  __shared__ u16 As[2048];   // 4 KB (64 x 32)
  __shared__ u16 Bs[2048];   // 4 KB
  const int K = DIi;
  const int idx = blockIdx.z + zbase;
  const u16* A  = (idx == 1) ? wkb : wqb;
  const u16* Bt = (idx == 0) ? wqb : (idx == 1) ? wkb
                  : wob + (size_t)(idx - 2) * Dd * DIi;
  u16* Ct = (idx == 0) ? Gt : (idx == 1) ? Gkt
            : Ut + (size_t)(idx - 2) * Dd * Dd;

  const int tid = threadIdx.x, lane = tid & 63, w = tid >> 6;
  const int wr = w >> 1, wc = w & 1;           // 2x2 waves, 32x32 each
  const int l15 = lane & 15, lg = lane >> 4;
  const long bm0 = (long)blockIdx.y * 64;
  const long bn0 = (long)blockIdx.x * 64;

  const u16* aS0 = A  + (bm0 + (tid >> 2)) * K + (tid & 3) * 8;
  const u16* bS0 = Bt + (bn0 + (tid >> 2)) * K + (tid & 3) * 8;
  u16* aD0 = As + w * 512;   // wave-uniform base (HW adds lane*16B)
  u16* bD0 = Bs + w * 512;

  f32x4 acc[2][2] = {};

  for (int k0 = 0; k0 < K; k0 += 32) {
    GLL(aS0 + k0, aD0);
    GLL(bS0 + k0, bD0);
    __syncthreads();
    bf16x8 af[2], bfv[2];
#pragma unroll
    for (int m = 0; m < 2; ++m)
      af[m] = *(const bf16x8*)(As + (wr * 32 + m * 16 + l15) * 32 + lg * 8);
#pragma unroll
    for (int n = 0; n < 2; ++n)
      bfv[n] = *(const bf16x8*)(Bs + (wc * 32 + n * 16 + l15) * 32 + lg * 8);
#pragma unroll
    for (int m = 0; m < 2; ++m)
#pragma unroll
      for (int n = 0; n < 2; ++n)
        acc[m][n] = __builtin_amdgcn_mfma_f32_16x16x32_bf16(af[m], bfv[n], acc[m][n], 0, 0, 0);
    __syncthreads();
  }

  // transposed store: Ct[col][row0..3] (rows consecutive -> ushort4)
#pragma unroll
  for (int m = 0; m < 2; ++m) {
    const int row0 = (int)bm0 + wr * 32 + m * 16 + lg * 4;
#pragma unroll
    for (int n = 0; n < 2; ++n) {
      const int col = (int)bn0 + wc * 32 + n * 16 + l15;
      ushort4 o;
      o.x = f2bu(acc[m][n][0]); o.y = f2bu(acc[m][n][1]);
      o.z = f2bu(acc[m][n][2]); o.w = f2bu(acc[m][n][3]);
      *(ushort4*)(Ct + (size_t)col * Dd + row0) = o;
    }
  }
}

// ====== megacb: C_b = xrnT_b @ xT_b^T, 64x64 tiles, grid (8,8,Bb)=512 blocks ======
__global__ __launch_bounds__(256) void megacb(
    const u16* __restrict__ xrnT, const u16* __restrict__ xT,
    u16* __restrict__ Cb)
{
  __shared__ u16 As[2048];   // 4 KB (64 x 32)
  __shared__ u16 Bs[2048];   // 4 KB
  const int K = Ss;
  const int z = blockIdx.z;
  const u16* A  = xrnT + (size_t)z * Dd * Ss;
  const u16* Bt = xT   + (size_t)z * Dd * Ss;
  u16* C = Cb + (size_t)z * Dd * Dd;

  const int tid = threadIdx.x, lane = tid & 63, w = tid >> 6;
  const int wr = w >> 1, wc = w & 1;           // 2x2 waves, 32x32 each
  const int l15 = lane & 15, lg = lane >> 4;
  const long bm0 = (long)blockIdx.y * 64;
  const long bn0 = (long)blockIdx.x * 64;

  const u16* aS0 = A  + (bm0 + (tid >> 2)) * K + (tid & 3) * 8;
  const u16* bS0 = Bt + (bn0 + (tid >> 2)) * K + (tid & 3) * 8;
  u16* aD0 = As + w * 512;
  u16* bD0 = Bs + w * 512;

  f32x4 acc[2][2] = {};

  for (int k0 = 0; k0 < K; k0 += 32) {
    GLL(aS0 + k0, aD0);
    GLL(bS0 + k0, bD0);
    __syncthreads();
    bf16x8 af[2], bfv[2];
#pragma unroll
    for (int m = 0; m < 2; ++m)
      af[m] = *(const bf16x8*)(As + (wr * 32 + m * 16 + l15) * 32 + lg * 8);
#pragma unroll
    for (int n = 0; n < 2; ++n)
      bfv[n] = *(const bf16x8*)(Bs + (wc * 32 + n * 16 + l15) * 32 + lg * 8);
#pragma unroll
    for (int m = 0; m < 2; ++m)
#pragma unroll
      for (int n = 0; n < 2; ++n)
        acc[m][n] = __builtin_amdgcn_mfma_f32_16x16x32_bf16(af[m], bfv[n], acc[m][n], 0, 0, 0);
    __syncthreads();
  }

#pragma unroll
  for (int m = 0; m < 2; ++m) {
    const long row0 = bm0 + wr * 32 + m * 16 + lg * 4;
#pragma unroll
    for (int n = 0; n < 2; ++n) {
      const long col = bn0 + wc * 32 + n * 16 + l15;
#pragma unroll
      for (int r = 0; r < 4; ++r)
        C[(row0 + r) * Dd + col] = f2bu(acc[m][n][r]);
    }
  }
}

// ====== megatb: T_b = C_b @ wv  (K=512, N=2048), 128^2 tiles, z=batch ======
__global__ __launch_bounds__(256) void megatb(
    const u16* __restrict__ Cb, const u16* __restrict__ wvT,
    u16* __restrict__ Tb)
{
  __shared__ u16 As[4096];
  __shared__ u16 Bs[4096];
  const int K = Dd, N = DIi;
  const int z = blockIdx.z;
  const u16* A  = Cb + (size_t)z * Dd * Dd;
  u16* C = Tb + (size_t)z * Dd * DIi;

  const int tid = threadIdx.x, lane = tid & 63, w = tid >> 6;
  const int wr = w >> 1, wc = w & 1;
  const int l15 = lane & 15, lg = lane >> 4;
  const long bm0 = (long)blockIdx.y * 128;
  const long bn0 = (long)blockIdx.x * 128;

  const int c0 = tid, c1 = tid + 256;
  const u16* aS0 = A   + (bm0 + (c0 >> 2)) * K + (c0 & 3) * 8;
  const u16* aS1 = A   + (bm0 + (c1 >> 2)) * K + (c1 & 3) * 8;
  const u16* bS0 = wvT + (bn0 + (c0 >> 2)) * K + (c0 & 3) * 8;
  const u16* bS1 = wvT + (bn0 + (c1 >> 2)) * K + (c1 & 3) * 8;
  u16* aD0 = As + w * 512;
  u16* aD1 = As + 2048 + w * 512;
  u16* bD0 = Bs + w * 512;
  u16* bD1 = Bs + 2048 + w * 512;

  f32x4 acc[4][4] = {};

  for (int k0 = 0; k0 < K; k0 += 32) {
    GLL(aS0 + k0, aD0);
    GLL(aS1 + k0, aD1);
    GLL(bS0 + k0, bD0);
    GLL(bS1 + k0, bD1);
    __syncthreads();
    bf16x8 af[4], bfv[4];
#pragma unroll
    for (int m = 0; m < 4; ++m)
      af[m] = *(const bf16x8*)(As + (wr * 64 + m * 16 + l15) * 32 + lg * 8);
#pragma unroll
    for (int n = 0; n < 4; ++n)
      bfv[n] = *(const bf16x8*)(Bs + (wc * 64 + n * 16 + l15) * 32 + lg * 8);
#pragma unroll
    for (int m = 0; m < 4; ++m)
#pragma unroll
      for (int n = 0; n < 4; ++n)
        acc[m][n] = __builtin_amdgcn_mfma_f32_16x16x32_bf16(af[m], bfv[n], acc[m][n], 0, 0, 0);
    __syncthreads();
  }

#pragma unroll
  for (int m = 0; m < 4; ++m) {
    const long row0 = bm0 + wr * 64 + m * 16 + lg * 4;
#pragma unroll
    for (int n = 0; n < 4; ++n) {
      const long col = bn0 + wc * 64 + n * 16 + l15;
#pragma unroll
      for (int r = 0; r < 4; ++r)
        C[(row0 + r) * N + col] = f2bu(acc[m][n][r]);
    }
  }
}

// ====== mega_nx: M x 512 GEMM (K=512) with x-restage epilogue ======
// MODE 0 (dual Gram): rows [0,Mm): nqsq via Gt; rows [Mm,2Mm): nksq via Gkt
// MODE 1 (AWO): acc = x@U_b tile; attnb = bf16(acc*rsqrt(nqsq) + x)
template<int MODE>
__global__ __launch_bounds__(256) void mega_nx(
    const u16* __restrict__ xb, const u16* __restrict__ Gt, const u16* __restrict__ Gkt,
    const u16* __restrict__ Ut,
    float* __restrict__ nqsq, float* __restrict__ nksq, u16* __restrict__ attnb)
{
  __shared__ u16 As[4096];    // 8 KB
  __shared__ u16 Bs[4096];    // 8 KB
  __shared__ u16 xs[16384];   // 32 KB x-tile restage
  const int K = Dd, N = Dd;

  const int tid = threadIdx.x, lane = tid & 63, w = tid >> 6;
  const int wr = w >> 1, wc = w & 1;
  const int l15 = lane & 15, lg = lane >> 4;
  const bool isK = (MODE == 0) && (blockIdx.y >= Mm / 128);
  const long bm0 = (long)(isK ? blockIdx.y - Mm / 128 : blockIdx.y) * 128;
  const long bn0 = (long)blockIdx.x * 128;
  const int bq = (int)(bm0 >> 12);
  const u16* Bt = (MODE == 0) ? (isK ? Gkt : Gt) : Ut + (size_t)bq * Dd * Dd;
  float* nsq = (MODE == 0) ? (isK ? nksq : nqsq) : nqsq;

  const int c0 = tid, c1 = tid + 256;
  const u16* aS0 = xb + (bm0 + (c0 >> 2)) * K + (c0 & 3) * 8;
  const u16* aS1 = xb + (bm0 + (c1 >> 2)) * K + (c1 & 3) * 8;
  const u16* bS0 = Bt + (bn0 + (c0 >> 2)) * K + (c0 & 3) * 8;
  const u16* bS1 = Bt + (bn0 + (c1 >> 2)) * K + (c1 & 3) * 8;
  u16* aD0 = As + w * 512;
  u16* aD1 = As + 2048 + w * 512;
  u16* bD0 = Bs + w * 512;
  u16* bD1 = Bs + 2048 + w * 512;

  f32x4 acc[4][4] = {};

  for (int k0 = 0; k0 < K; k0 += 32) {
    GLL(aS0 + k0, aD0);
    GLL(aS1 + k0, aD1);
    GLL(bS0 + k0, bD0);
    GLL(bS1 + k0, bD1);
    __syncthreads();
    bf16x8 af[4], bfv[4];
#pragma unroll
    for (int m = 0; m < 4; ++m)
      af[m] = *(const bf16x8*)(As + (wr * 64 + m * 16 + l15) * 32 + lg * 8);
#pragma unroll
    for (int n = 0; n < 4; ++n)
      bfv[n] = *(const bf16x8*)(Bs + (wc * 64 + n * 16 + l15) * 32 + lg * 8);
#pragma unroll
    for (int m = 0; m < 4; ++m)
#pragma unroll
      for (int n = 0; n < 4; ++n)
        acc[m][n] = __builtin_amdgcn_mfma_f32_16x16x32_bf16(af[m], bfv[n], acc[m][n], 0, 0, 0);
    __syncthreads();
  }

  // restage block's x tile [128 rows x 128 cols] with slot-XOR swizzle
#pragma unroll
  for (int i = 0; i < 8; ++i) {
    const int c = i * 256 + tid;
    const int rowL = c >> 4;
    const int srcslot = (c & 15) ^ (rowL & 15);
    const u16* src = xb + (size_t)(bm0 + rowL) * Dd + bn0 + srcslot * 8;
    GLL(src, xs + i * 2048 + w * 512);
  }
  asm volatile("s_waitcnt vmcnt(0)" ::: "memory");
  __builtin_amdgcn_s_barrier();

#define XV(RL, CL) bfu(xs[(RL) * 128 + ((((CL) >> 3) ^ ((RL) & 15)) << 3) + ((CL) & 7)])

  if constexpr (MODE == 0) {
    float sk[16];
#pragma unroll
    for (int i = 0; i < 16; ++i) sk[i] = 0.f;
#pragma unroll
    for (int m = 0; m < 4; ++m) {
#pragma unroll
      for (int n = 0; n < 4; ++n) {
        const int colL = wc * 64 + n * 16 + l15;
#pragma unroll
        for (int r = 0; r < 4; ++r) {
          const int rowL = wr * 64 + m * 16 + lg * 4 + r;
          sk[m * 4 + r] += acc[m][n][r] * XV(rowL, colL);
        }
      }
    }
#pragma unroll
    for (int i = 0; i < 16; ++i) {
#pragma unroll
      for (int off = 1; off < 16; off <<= 1)
        sk[i] += __shfl_xor(sk[i], off, 64);
    }
    if (l15 == 0) {
#pragma unroll
      for (int m = 0; m < 4; ++m)
#pragma unroll
        for (int r = 0; r < 4; ++r)
          atomicAdd(&nsq[bm0 + wr * 64 + m * 16 + lg * 4 + r], sk[m * 4 + r]);
    }
  } else {
#pragma unroll
    for (int m = 0; m < 4; ++m) {
      const long row0 = bm0 + wr * 64 + m * 16 + lg * 4;
      float rq[4];
#pragma unroll
      for (int r = 0; r < 4; ++r)
        rq[r] = 1.f / fmaxf(sqrtf(fmaxf(nqsq[row0 + r], 0.f)), 1e-12f);
#pragma unroll
      for (int n = 0; n < 4; ++n) {
        const int colL = wc * 64 + n * 16 + l15;
#pragma unroll
        for (int r = 0; r < 4; ++r) {
          const int rowL = wr * 64 + m * 16 + lg * 4 + r;
          attnb[(row0 + r) * N + bn0 + colL] = f2bu(acc[m][n][r] * rq[r] + XV(rowL, colL));
        }
      }
    }
  }
#undef XV
}

extern "C" void kernel_launch(void* const* d_in, const int* in_sizes, int n_in,
                              void* d_out, int out_size, void* d_ws, size_t ws_size,
                              hipStream_t stream) {
  const float* x  = (const float*)d_in[0];
  const float* wq = (const float*)d_in[1];
  const float* wk = (const float*)d_in[2];
  const float* wv = (const float*)d_in[3];
  const float* wo = (const float*)d_in[4];
  const float* w1 = (const float*)d_in[5];
  const float* b1 = (const float*)d_in[6];
  const float* w2 = (const float*)d_in[7];
  const float* b2 = (const float*)d_in[8];
  float* out = (float*)d_out;

  // workspace carve-up: ~219.5 MB total (ws_size evidence: 236 MB OK, 324 MB faults)
  char* p = (char*)d_ws;
  auto take = [&](size_t bytes) {
    char* r = p; p += (bytes + 255) & ~(size_t)255; return r;
  };
  u16*   xb    = (u16*)take((size_t)Mm * Dd * 2);        // 33.5 MB
  u16*   wvT   = (u16*)take((size_t)DIi * Dd * 2);
  u16*   w1T   = (u16*)take((size_t)DIi * Dd * 2);
  u16*   woT   = (u16*)take((size_t)Dd * DIi * 2);
  u16*   w2T   = (u16*)take((size_t)Dd * DIi * 2);
  u16*   wqb   = (u16*)take((size_t)Dd * DIi * 2);
  u16*   wkb   = (u16*)take((size_t)Dd * DIi * 2);
  u16*   Gt    = (u16*)take((size_t)Dd * Dd * 2);
  u16*   Gkt   = (u16*)take((size_t)Dd * Dd * 2);
  u16*   Ut    = (u16*)take((size_t)Bb * Dd * Dd * 2);   // 4.2 MB
  u16*   buf1  = (u16*)take((size_t)Mm * DIi * 2);       // 134 MB: pre-FFN scratch, then h
  u16*   attnb = (u16*)take((size_t)Mm * Dd * 2);        // 33.5 MB
  float* nksq  = (float*)take((size_t)Mm * 4);           // contiguous: nksq,nqsq,kvp
  float* nqsq  = (float*)take((size_t)Mm * 4);
  float* kvp   = (float*)take((size_t)Bb * DIi * 4);
  // sub-carve inside buf1 — all lifetimes end before FFN1 writes h into buf1
  u16* xT   = buf1;                                          // 33.5 MB
  u16* xrnT = buf1 + (size_t)Mm * Dd;                        // 33.5 MB
  u16* Tb   = buf1 + 2 * (size_t)Mm * Dd;                    // 16.8 MB
  u16* Cb   = buf1 + 2 * (size_t)Mm * Dd + (size_t)Bb * Dd * DIi;        // 4.2 MB
  u16* wob  = buf1 + 2 * (size_t)Mm * Dd + (size_t)Bb * Dd * DIi
                   + (size_t)Bb * Dd * Dd;                   // 16.8 MB (ends at 104.9 MB)
  (void)in_sizes; (void)n_in; (void)out_size; (void)ws_size;

  // prep: zero(nksq,nqsq,kvp) + conv x + tr wv/w1/wo/w2 + conv wq/wk
  prep<<<8512, 256, 0, stream>>>(x, xb, wv, w1, wo, w2, wq, wk,
                                 wvT, w1T, woT, w2T, wqb, wkb, nksq);

  // Gq = wqb@wqb^T ; Gk = wkb@wkb^T  (64^2 tiles, 128 blocks)
  mega64t<<<dim3(8, 8, 2), 256, 0, stream>>>(wqb, wkb, nullptr, Gt, Gkt, Ut, 0);

  // nqsq & nksq in one dispatch: rowdot(x@G, x)
  mega_nx<0><<<dim3(4, 2 * Mm / 128), 256, 0, stream>>>(
      xb, Gt, Gkt, nullptr, nqsq, nksq, nullptr);

  // xT / xrnT (rn = rsqrt(nksq) folded)
  tr_x<<<dim3(Dd / 32, Ss / 32, Bb), dim3(32, 8), 0, stream>>>(xb, nksq, xT, xrnT);

  // C_b = xrnT_b @ xT_b^T   [512x512 per batch], 64^2 tiles, 512 blocks
  megacb<<<dim3(8, 8, Bb), 256, 0, stream>>>(xrnT, xT, Cb);

  // T_b = C_b @ wv          [512x2048 per batch]
  megatb<<<dim3(16, 4, Bb), 256, 0, stream>>>(Cb, wvT, Tb);

  // kv[b,e] += sum_d wkb[d,e] * T_b[d,e]   (512 blocks, d-chunked atomics)
  colsum_kv<<<dim3(8, Bb, 8), 256, 0, stream>>>(wkb, Tb, kvp);

  // wob[b] = woT * kv[b]
  build_wob<<<dim3(512, Bb), 256, 0, stream>>>(woT, kvp, wob);

  // U_b = wqb @ wob_b^T -> Ut  (64^2 tiles, 512 blocks)
  mega64t<<<dim3(8, 8, 8), 256, 0, stream>>>(wqb, wkb, wob, Gt, Gkt, Ut, 2);

  // attn = (x@U_b)*rsqrt(nqsq) + x -> attnb
  mega_nx<1><<<dim3(4, Mm / 128), 256, 0, stream>>>(
      xb, nullptr, nullptr, Ut, nqsq, nullptr, attnb);

  // h = relu(attn @ w1 + b1) -> buf1 (overwrites dead xT/xrnT/Tb/Cb/wob)
  gemm8<G_FFN1><<<dim3(DIi / 256, Mm / 256), 512, 0, stream>>>(
      attnb, w1T, DIi, Dd, buf1, nullptr, nullptr, b1);

  // out = h @ w2 + b2 + attn
  gemm8<G_FFN2><<<dim3(Dd / 256, Mm / 256), 512, 0, stream>>>(
      buf1, w2T, Dd, DIi, nullptr, out, attnb, b2);
}